// Round 1
// baseline (9554.424 us; speedup 1.0000x reference)
//
#include <hip/hip_runtime.h>
#include <math.h>
#include <float.h>

#define NB     64      // batch
#define S_EN   50
#define S_DE   50
#define EMB_E  64
#define EMB_D  32
#define HID    32
#define G4     128     // 4*H
#define DE_VSZ 19000

__device__ __forceinline__ float sigmoidf_(float x) { return 1.0f / (1.0f + expf(-x)); }

// One block per batch element. Encoder (50 steps) then decoder (49 steps with
// greedy argmax feedback) run entirely inside the block; batch elements are
// independent, so no inter-block communication is needed.
__global__ __launch_bounds__(256) void seq2seq_kernel(
    const int*   __restrict__ en_batch,   // (B, S_EN)
    const int*   __restrict__ en_lens,    // (B,)
    const int*   __restrict__ de_batch,   // (B, S_DE)
    const float* __restrict__ en_emb,     // (EN_V, EMB_E)
    const float* __restrict__ eWih,       // (4H, EMB_E)
    const float* __restrict__ eWhh,       // (4H, H)
    const float* __restrict__ ebih,       // (4H,)
    const float* __restrict__ ebhh,       // (4H,)
    const float* __restrict__ de_emb,     // (DE_V, EMB_D)
    const float* __restrict__ dWih,       // (4H, EMB_D)
    const float* __restrict__ dWhh,       // (4H, H)
    const float* __restrict__ dbih,       // (4H,)
    const float* __restrict__ dbhh,       // (4H,)
    const float* __restrict__ fcW,        // (DE_V, H)
    const float* __restrict__ fcb,        // (DE_V,)
    float*       __restrict__ out)        // (B, S_DE, DE_V)
{
    __shared__ __align__(16) float sh[HID];   // hidden state
    __shared__ float sc[HID];                 // cell state
    __shared__ float sx[EMB_E];               // current input embedding
    __shared__ float sg[G4];                  // pre-activation gates
    __shared__ float wbest[4];
    __shared__ int   widx[4];
    __shared__ int   stok;

    const int b   = blockIdx.x;
    const int tid = threadIdx.x;

    if (tid < HID) { sh[tid] = 0.0f; sc[tid] = 0.0f; }
    __syncthreads();

    // ---------------- encoder ----------------
    // Reference masks updates for t >= len; since the mask is monotone we can
    // simply stop at len (state frozen afterwards).
    const int len = en_lens[b];
    for (int t = 0; t < len; ++t) {
        const int tok = en_batch[b * S_EN + t];
        if (tid < EMB_E) sx[tid] = en_emb[(size_t)tok * EMB_E + tid];
        __syncthreads();
        if (tid < G4) {
            float g = ebih[tid] + ebhh[tid];
            const float* wr = &eWih[(size_t)tid * EMB_E];
            #pragma unroll
            for (int k = 0; k < EMB_E; ++k) g = fmaf(sx[k], wr[k], g);
            const float* hr = &eWhh[(size_t)tid * HID];
            #pragma unroll
            for (int k = 0; k < HID; ++k) g = fmaf(sh[k], hr[k], g);
            sg[tid] = g;
        }
        __syncthreads();
        if (tid < HID) {
            const float i  = sigmoidf_(sg[tid]);
            const float f  = sigmoidf_(sg[HID + tid]);
            const float gg = tanhf(sg[2 * HID + tid]);
            const float o  = sigmoidf_(sg[3 * HID + tid]);
            const float c  = f * sc[tid] + i * gg;
            sc[tid] = c;
            sh[tid] = o * tanhf(c);
        }
        __syncthreads();
    }

    // ---------------- decoder ----------------
    float* orow = out + (size_t)b * S_DE * DE_VSZ;

    // out[:, 0, :] = 0  (d_out is poisoned before every launch)
    for (int v = tid; v < DE_VSZ; v += 256) orow[v] = 0.0f;

    if (tid == 0) stok = de_batch[b * S_DE + 0];
    __syncthreads();

    const int sub = tid & 7;   // k-slice (4 floats each) within a row
    const int rg  = tid >> 3;  // row group 0..31

    for (int s = 1; s < S_DE; ++s) {
        const int tok = stok;
        if (tid < EMB_D) sx[tid] = de_emb[(size_t)tok * EMB_D + tid];
        __syncthreads();
        if (tid < G4) {
            float g = dbih[tid] + dbhh[tid];
            const float* wr = &dWih[(size_t)tid * EMB_D];
            #pragma unroll
            for (int k = 0; k < EMB_D; ++k) g = fmaf(sx[k], wr[k], g);
            const float* hr = &dWhh[(size_t)tid * HID];
            #pragma unroll
            for (int k = 0; k < HID; ++k) g = fmaf(sh[k], hr[k], g);
            sg[tid] = g;
        }
        __syncthreads();
        if (tid < HID) {
            const float i  = sigmoidf_(sg[tid]);
            const float f  = sigmoidf_(sg[HID + tid]);
            const float gg = tanhf(sg[2 * HID + tid]);
            const float o  = sigmoidf_(sg[3 * HID + tid]);
            const float c  = f * sc[tid] + i * gg;
            sc[tid] = c;
            sh[tid] = o * tanhf(c);
        }
        __syncthreads();

        // ---- fc + argmax: 8 threads per row, coalesced 1 KiB/wave loads ----
        const float4 hv = *(const float4*)&sh[sub * 4];
        float best = -FLT_MAX;
        int   bidx = 0x7FFFFFFF;
        float* os = orow + (size_t)s * DE_VSZ;

        for (int it = 0; it < (DE_VSZ + 31) / 32; ++it) {
            const int v = it * 32 + rg;
            float part = 0.0f;
            if (v < DE_VSZ) {
                const float4 w = *(const float4*)&fcW[(size_t)v * HID + sub * 4];
                part = hv.x * w.x + hv.y * w.y + hv.z * w.z + hv.w * w.w;
            }
            part += __shfl_xor(part, 1);
            part += __shfl_xor(part, 2);
            part += __shfl_xor(part, 4);
            if (sub == 0 && v < DE_VSZ) {
                const float logit = part + fcb[v];
                os[v] = logit;
                // v strictly increases per thread -> strict '>' keeps first max
                if (logit > best) { best = logit; bidx = v; }
            }
        }

        // argmax reduce across 256 threads; ties -> smallest index (jnp.argmax)
        for (int off = 1; off < 64; off <<= 1) {
            const float ov = __shfl_xor(best, off);
            const int   oi = __shfl_xor(bidx, off);
            if (ov > best || (ov == best && oi < bidx)) { best = ov; bidx = oi; }
        }
        if ((tid & 63) == 0) { wbest[tid >> 6] = best; widx[tid >> 6] = bidx; }
        __syncthreads();
        if (tid == 0) {
            float bb = wbest[0]; int bi = widx[0];
            #pragma unroll
            for (int w = 1; w < 4; ++w) {
                if (wbest[w] > bb || (wbest[w] == bb && widx[w] < bi)) {
                    bb = wbest[w]; bi = widx[w];
                }
            }
            stok = bi;
        }
        __syncthreads();
    }
}

extern "C" void kernel_launch(void* const* d_in, const int* in_sizes, int n_in,
                              void* d_out, int out_size, void* d_ws, size_t ws_size,
                              hipStream_t stream) {
    (void)in_sizes; (void)n_in; (void)d_ws; (void)ws_size; (void)out_size;
    const int*   en_batch = (const int*)  d_in[0];
    const int*   en_lens  = (const int*)  d_in[1];
    const int*   de_batch = (const int*)  d_in[2];
    const float* en_emb   = (const float*)d_in[3];
    const float* eWih     = (const float*)d_in[4];
    const float* eWhh     = (const float*)d_in[5];
    const float* ebih     = (const float*)d_in[6];
    const float* ebhh     = (const float*)d_in[7];
    const float* de_emb   = (const float*)d_in[8];
    const float* dWih     = (const float*)d_in[9];
    const float* dWhh     = (const float*)d_in[10];
    const float* dbih     = (const float*)d_in[11];
    const float* dbhh     = (const float*)d_in[12];
    const float* fcW      = (const float*)d_in[13];
    const float* fcb      = (const float*)d_in[14];
    float* out = (float*)d_out;

    seq2seq_kernel<<<NB, 256, 0, stream>>>(
        en_batch, en_lens, de_batch, en_emb, eWih, eWhh, ebih, ebhh,
        de_emb, dWih, dWhh, dbih, dbhh, fcW, fcb, out);
}

// Round 2
// 3471.952 us; speedup vs baseline: 2.7519x; 2.7519x over previous
//
#include <hip/hip_runtime.h>
#include <math.h>
#include <float.h>

#define NB     64      // batch
#define S_EN   50
#define S_DE   50
#define EMB_E  64
#define EMB_D  32
#define HID    32
#define G4     128     // 4*H
#define DE_VSZ 19000
#define OUT_B  (S_DE * DE_VSZ)   // per-batch output stride (950000)

#define NBLK   256     // grid: 2 batch-halves x 128 vocab slices
#define NTHR   256
#define NJB    32      // batches per block
#define ISL    128     // vocab slices
#define NRS    192     // rows per slice (3 x 64)
#define RPL    3       // rows per lane

__device__ __forceinline__ float sigmoidf_(float x) { return 1.0f / (1.0f + expf(-x)); }

// monotone float->uint mapping: a<b  <=>  ordf(a)<ordf(b)
__device__ __forceinline__ unsigned ordf_(float f) {
    unsigned u = __float_as_uint(f);
    return (u & 0x80000000u) ? ~u : (u | 0x80000000u);
}

// Persistent whole-chip kernel. Blocks 0..63 own one batch element each
// (encoder + decoder LSTM + argmax reduce). Every block additionally computes
// a (192-row x 32-batch) slice of the FC each decoder step, with its fcW rows
// held in VGPRs. Cross-block handshake: device-scope counters in d_ws
// (release/acquire + __threadfence). Grid(256) <= CU count and capacity is
// >=1 block/CU at any VGPR usage, so all blocks are co-resident -> spins safe.
__global__ __launch_bounds__(NTHR, 1) void seq2seq_coop(
    const int*   __restrict__ en_batch,   // (B, S_EN)
    const int*   __restrict__ en_lens,    // (B,)
    const int*   __restrict__ de_batch,   // (B, S_DE)
    const float* __restrict__ en_emb,     // (EN_V, EMB_E)
    const float* __restrict__ eWih, const float* __restrict__ eWhh,
    const float* __restrict__ ebih, const float* __restrict__ ebhh,
    const float* __restrict__ de_emb,     // (DE_V, EMB_D)
    const float* __restrict__ dWih, const float* __restrict__ dWhh,
    const float* __restrict__ dbih, const float* __restrict__ dbhh,
    const float* __restrict__ fcW,        // (DE_V, H)
    const float* __restrict__ fcb,        // (DE_V,)
    float*       __restrict__ out,        // (B, S_DE, DE_V)
    unsigned* hctr, unsigned* bctr,       // handshake counters (zeroed host-side)
    float* hbuf,                          // (B, H) published hidden state
    unsigned long long* wbest)            // (B, ISL) packed argmax partials
{
    const int tid  = threadIdx.x;
    const int wv   = tid >> 6;
    const int lane = tid & 63;
    const int blk  = blockIdx.x;
    const int q    = blk >> 7;          // batch-half 0/1
    const int isl  = blk & (ISL - 1);   // vocab slice

    __shared__ float s_h[HID], s_c[HID], s_x[EMB_E], s_g[G4];
    __shared__ __align__(16) float s_hj[NJB * HID];   // staged h for my 32 batches
    __shared__ unsigned long long s_red[4];
    __shared__ int s_tok;

    // ---- zero out[:, 0, :] (d_out is poisoned before every launch) ----
    for (int idx = blk * NTHR + tid; idx < NB * DE_VSZ; idx += NBLK * NTHR) {
        int bb = idx / DE_VSZ;
        int v  = idx - bb * DE_VSZ;
        out[(size_t)bb * OUT_B + v] = 0.0f;
    }

    // ---- hoist my fcW rows + bias into registers (never re-read) ----
    float wr[RPL][HID];
    float br[RPL];
    int   grow[RPL];
    bool  rv[RPL];
    #pragma unroll
    for (int ii = 0; ii < RPL; ++ii) {
        const int gr = isl * NRS + ii * 64 + lane;
        grow[ii] = gr;
        rv[ii]   = (gr < DE_VSZ);
        br[ii]   = rv[ii] ? fcb[gr] : 0.0f;
        #pragma unroll
        for (int kc = 0; kc < 8; ++kc) {
            float4 w4 = rv[ii] ? *(const float4*)&fcW[(size_t)gr * HID + kc * 4]
                               : make_float4(0.f, 0.f, 0.f, 0.f);
            wr[ii][kc * 4 + 0] = w4.x; wr[ii][kc * 4 + 1] = w4.y;
            wr[ii][kc * 4 + 2] = w4.z; wr[ii][kc * 4 + 3] = w4.w;
        }
    }

    // ---- encoder (owner blocks only). Mask is monotone -> stop at len ----
    int tok = 0;
    const int b = blk;   // owner batch id (blocks 0..63)
    if (blk < NB) {
        if (tid < HID) { s_h[tid] = 0.0f; s_c[tid] = 0.0f; }
        __syncthreads();
        const int len = en_lens[b];
        for (int t = 0; t < len; ++t) {
            const int etok = en_batch[b * S_EN + t];
            if (tid < EMB_E) s_x[tid] = en_emb[(size_t)etok * EMB_E + tid];
            __syncthreads();
            if (tid < G4) {
                float g = ebih[tid] + ebhh[tid];
                const float* wrow = &eWih[(size_t)tid * EMB_E];
                #pragma unroll
                for (int k = 0; k < EMB_E; ++k) g = fmaf(s_x[k], wrow[k], g);
                const float* hrow = &eWhh[(size_t)tid * HID];
                #pragma unroll
                for (int k = 0; k < HID; ++k) g = fmaf(s_h[k], hrow[k], g);
                s_g[tid] = g;
            }
            __syncthreads();
            if (tid < HID) {
                const float i  = sigmoidf_(s_g[tid]);
                const float f  = sigmoidf_(s_g[HID + tid]);
                const float gg = tanhf(s_g[2 * HID + tid]);
                const float o  = sigmoidf_(s_g[3 * HID + tid]);
                const float c  = f * s_c[tid] + i * gg;
                s_c[tid] = c;
                s_h[tid] = o * tanhf(c);
            }
            __syncthreads();
        }
        tok = de_batch[b * S_DE + 0];
    }

    // ---- decoder: 49 steps ----
    for (int s = 1; s < S_DE; ++s) {
        // phase A (owners): LSTM step, publish h
        if (blk < NB) {
            if (tid < EMB_D) s_x[tid] = de_emb[(size_t)tok * EMB_D + tid];
            __syncthreads();
            if (tid < G4) {
                float g = dbih[tid] + dbhh[tid];
                const float* wrow = &dWih[(size_t)tid * EMB_D];
                #pragma unroll
                for (int k = 0; k < EMB_D; ++k) g = fmaf(s_x[k], wrow[k], g);
                const float* hrow = &dWhh[(size_t)tid * HID];
                #pragma unroll
                for (int k = 0; k < HID; ++k) g = fmaf(s_h[k], hrow[k], g);
                s_g[tid] = g;
            }
            __syncthreads();
            if (tid < HID) {
                const float i  = sigmoidf_(s_g[tid]);
                const float f  = sigmoidf_(s_g[HID + tid]);
                const float gg = tanhf(s_g[2 * HID + tid]);
                const float o  = sigmoidf_(s_g[3 * HID + tid]);
                const float c  = f * s_c[tid] + i * gg;
                s_c[tid] = c;
                const float hn = o * tanhf(c);
                s_h[tid] = hn;
                hbuf[b * HID + tid] = hn;    // publish
            }
            __syncthreads();
            if (tid == 0) {
                __threadfence();
                __hip_atomic_fetch_add(hctr, 1u, __ATOMIC_RELEASE, __HIP_MEMORY_SCOPE_AGENT);
            }
        }

        // all blocks: wait until all 64 h's for step s are published
        if (tid == 0) {
            const unsigned tgt = (unsigned)(NB * s);
            while (__hip_atomic_load(hctr, __ATOMIC_ACQUIRE, __HIP_MEMORY_SCOPE_AGENT) < tgt)
                __builtin_amdgcn_s_sleep(2);
            __threadfence();
        }
        __syncthreads();

        // stage my 32 h vectors (1024 floats) into LDS
        {
            const float4* src = (const float4*)(hbuf + q * NJB * HID);
            ((float4*)s_hj)[tid] = src[tid];   // exactly 256 float4
        }
        __syncthreads();

        // phase B: FC slice (192 rows x 32 batches) + per-batch wave argmax
        #pragma unroll 1
        for (int jj = 0; jj < 8; ++jj) {
            const int jloc = wv * 8 + jj;
            const int gj   = q * NJB + jloc;
            const float4* hj4 = (const float4*)&s_hj[jloc * HID];
            float a0 = br[0], a1 = br[1], a2 = br[2];
            #pragma unroll
            for (int kc = 0; kc < 8; ++kc) {
                const float4 h4 = hj4[kc];
                a0 = fmaf(wr[0][kc*4+0], h4.x, a0); a1 = fmaf(wr[1][kc*4+0], h4.x, a1); a2 = fmaf(wr[2][kc*4+0], h4.x, a2);
                a0 = fmaf(wr[0][kc*4+1], h4.y, a0); a1 = fmaf(wr[1][kc*4+1], h4.y, a1); a2 = fmaf(wr[2][kc*4+1], h4.y, a2);
                a0 = fmaf(wr[0][kc*4+2], h4.z, a0); a1 = fmaf(wr[1][kc*4+2], h4.z, a1); a2 = fmaf(wr[2][kc*4+2], h4.z, a2);
                a0 = fmaf(wr[0][kc*4+3], h4.w, a0); a1 = fmaf(wr[1][kc*4+3], h4.w, a1); a2 = fmaf(wr[2][kc*4+3], h4.w, a2);
            }
            float* od = out + (size_t)gj * OUT_B + (size_t)s * DE_VSZ;
            unsigned long long key = 0ull;
            if (rv[0]) { od[grow[0]] = a0;
                key = ((unsigned long long)ordf_(a0) << 32) | (unsigned)~grow[0]; }
            if (rv[1]) { od[grow[1]] = a1;
                unsigned long long k2 = ((unsigned long long)ordf_(a1) << 32) | (unsigned)~grow[1];
                if (k2 > key) key = k2; }
            if (rv[2]) { od[grow[2]] = a2;
                unsigned long long k2 = ((unsigned long long)ordf_(a2) << 32) | (unsigned)~grow[2];
                if (k2 > key) key = k2; }
            // wave argmax (max key = max logit, ties -> smallest index)
            #pragma unroll
            for (int off = 1; off < 64; off <<= 1) {
                const unsigned long long ok = __shfl_xor(key, off);
                if (ok > key) key = ok;
            }
            if (lane == 0) wbest[(size_t)gj * ISL + isl] = key;
        }
        __syncthreads();
        if (tid == 0) {
            __threadfence();
            __hip_atomic_fetch_add(bctr, 1u, __ATOMIC_RELEASE, __HIP_MEMORY_SCOPE_AGENT);
        }

        // phase C (owners): wait for all slices, reduce 128 partials -> token
        if (blk < NB) {
            if (tid == 0) {
                const unsigned tgt = (unsigned)(NBLK * s);
                while (__hip_atomic_load(bctr, __ATOMIC_ACQUIRE, __HIP_MEMORY_SCOPE_AGENT) < tgt)
                    __builtin_amdgcn_s_sleep(2);
                __threadfence();
            }
            __syncthreads();
            unsigned long long key = (tid < ISL) ? wbest[(size_t)b * ISL + tid] : 0ull;
            #pragma unroll
            for (int off = 1; off < 64; off <<= 1) {
                const unsigned long long ok = __shfl_xor(key, off);
                if (ok > key) key = ok;
            }
            if (lane == 0) s_red[wv] = key;
            __syncthreads();
            if (tid == 0) {
                unsigned long long kk = s_red[0];
                if (s_red[1] > kk) kk = s_red[1];
                if (s_red[2] > kk) kk = s_red[2];
                if (s_red[3] > kk) kk = s_red[3];
                s_tok = (int)(~(unsigned)kk);
            }
            __syncthreads();
            tok = s_tok;
        }
    }
}

extern "C" void kernel_launch(void* const* d_in, const int* in_sizes, int n_in,
                              void* d_out, int out_size, void* d_ws, size_t ws_size,
                              hipStream_t stream) {
    (void)in_sizes; (void)n_in; (void)out_size; (void)ws_size;
    const int*   en_batch = (const int*)  d_in[0];
    const int*   en_lens  = (const int*)  d_in[1];
    const int*   de_batch = (const int*)  d_in[2];
    const float* en_emb   = (const float*)d_in[3];
    const float* eWih     = (const float*)d_in[4];
    const float* eWhh     = (const float*)d_in[5];
    const float* ebih     = (const float*)d_in[6];
    const float* ebhh     = (const float*)d_in[7];
    const float* de_emb   = (const float*)d_in[8];
    const float* dWih     = (const float*)d_in[9];
    const float* dWhh     = (const float*)d_in[10];
    const float* dbih     = (const float*)d_in[11];
    const float* dbhh     = (const float*)d_in[12];
    const float* fcW      = (const float*)d_in[13];
    const float* fcb      = (const float*)d_in[14];
    float* out = (float*)d_out;

    char* ws = (char*)d_ws;
    unsigned* hctr = (unsigned*)(ws + 0);
    unsigned* bctr = (unsigned*)(ws + 64);
    float*    hbuf = (float*)(ws + 256);                       // 8 KB
    unsigned long long* wbest = (unsigned long long*)(ws + 256 + 8192);  // 64 KB

    // zero the handshake counters (graph-capture-safe)
    hipMemsetAsync(ws, 0, 256, stream);

    seq2seq_coop<<<NBLK, NTHR, 0, stream>>>(
        en_batch, en_lens, de_batch, en_emb, eWih, eWhh, ebih, ebhh,
        de_emb, dWih, dWhh, dbih, dbhh, fcW, fcb, out,
        hctr, bctr, hbuf, wbest);
}

// Round 3
// 2872.063 us; speedup vs baseline: 3.3267x; 1.2089x over previous
//
#include <hip/hip_runtime.h>
#include <math.h>
#include <float.h>

#define NB     64      // batch
#define S_EN   50
#define S_DE   50
#define EMB_E  64
#define EMB_D  32
#define HID    32
#define G4     128     // 4*H
#define DE_VSZ 19000
#define OUT_B  (S_DE * DE_VSZ)

#define NBLK   256     // 2 batch-halves x 128 vocab slices
#define NTHR   256
#define NJB    32      // batches per half
#define ISL    128     // vocab slices per half
#define NRS    192     // fc rows per slice
#define RPL    3       // fc rows per lane

#define XROW   68      // s_xh row stride (x[32]|h[32] + pad4)
#define GROWS  132     // s_g row stride (128 gates + pad4)
#define EROW   97      // encoder weight row stride (96 + 1) -> conflict-free

typedef unsigned long long ull;

__device__ __forceinline__ float sigmoidf_(float x) { return 1.0f / (1.0f + expf(-x)); }

// monotone float->uint: a<b <=> ordf(a)<ordf(b)
__device__ __forceinline__ unsigned ordf_(float f) {
    unsigned u = __float_as_uint(f);
    return (u & 0x80000000u) ? ~u : (u | 0x80000000u);
}

// One sync hop per decoder step, no atomic RMWs, hot state in VGPR/LDS.
// Blocks (q,isl): q = half (32 batches), isl = vocab slice (192 rows).
// Each block redundantly runs the LSTM for its 32 batches (deterministic ->
// identical across blocks), computes its logit slice + packed argmax key,
// release-stores a per-slice flag, polls the 128 flags of its half (acquire
// loads, no RMW), reads keys (double-buffered by step parity), reduces the
// next token locally. Encoder on 64 owner blocks, published once via flags.
__global__ __launch_bounds__(NTHR, 1) void seq2seq_onehop(
    const int*   __restrict__ en_batch, const int* __restrict__ en_lens,
    const int*   __restrict__ de_batch,
    const float* __restrict__ en_emb,
    const float* __restrict__ eWih, const float* __restrict__ eWhh,
    const float* __restrict__ ebih, const float* __restrict__ ebhh,
    const float* __restrict__ de_emb,
    const float* __restrict__ dWih, const float* __restrict__ dWhh,
    const float* __restrict__ dbih, const float* __restrict__ dbhh,
    const float* __restrict__ fcW,  const float* __restrict__ fcb,
    float*       __restrict__ out,
    int* eflag,          // (64,)  encoder-done flags
    int* sflag,          // (2,128) per-slice step flags
    float* hc_out,       // (64, 64) encoder h|c
    ull*  gkeys)         // (2, 64, 128) packed argmax keys, parity-buffered
{
    const int tid  = threadIdx.x;
    const int wv   = tid >> 6;
    const int lane = tid & 63;
    const int blk  = blockIdx.x;
    const int q    = blk >> 7;
    const int isl  = blk & (ISL - 1);

    __shared__ __align__(16) float s_xh[NJB * XROW];   // x|h per batch
    __shared__ __align__(16) float s_g [NJB * GROWS];  // gates per batch
    __shared__ __align__(16) float s_c [NJB * HID];    // cell state
    __shared__ float s_ew[G4 * EROW];                  // encoder weights (owners)
    __shared__ float s_eg[G4], s_ex[96], s_ecell[HID];
    __shared__ int   s_tok[NJB];
    __shared__ int   s_done;

    // ---- zero out[:, 0, :] ----
    for (int idx = blk * NTHR + tid; idx < NB * DE_VSZ; idx += NBLK * NTHR) {
        int bb = idx / DE_VSZ;
        int v  = idx - bb * DE_VSZ;
        out[(size_t)bb * OUT_B + v] = 0.0f;
    }

    // ---- fc slice rows -> VGPRs (round-2 layout, never re-read) ----
    float wr[RPL][HID], br[RPL];
    int   grow[RPL];
    bool  rv[RPL];
    #pragma unroll
    for (int ii = 0; ii < RPL; ++ii) {
        const int gr = isl * NRS + ii * 64 + lane;
        grow[ii] = gr;
        rv[ii]   = (gr < DE_VSZ);
        br[ii]   = rv[ii] ? fcb[gr] : 0.0f;
        #pragma unroll
        for (int kc = 0; kc < 8; ++kc) {
            float4 w4 = rv[ii] ? *(const float4*)&fcW[(size_t)gr * HID + kc * 4]
                               : make_float4(0.f, 0.f, 0.f, 0.f);
            wr[ii][kc*4+0] = w4.x; wr[ii][kc*4+1] = w4.y;
            wr[ii][kc*4+2] = w4.z; wr[ii][kc*4+3] = w4.w;
        }
    }

    // ---- decoder LSTM weights -> VGPRs: 2 gates/thread {gp, 64+gp} ----
    const int gp = tid & 63;
    const int jh = tid >> 6;   // batch octet 0..3
    float wA[64], wB[64];
    {
        const float4* a4 = (const float4*)&dWih[gp * EMB_D];
        const float4* b4 = (const float4*)&dWih[(64 + gp) * EMB_D];
        #pragma unroll
        for (int c = 0; c < 8; ++c) {
            float4 va = a4[c], vb = b4[c];
            wA[c*4+0]=va.x; wA[c*4+1]=va.y; wA[c*4+2]=va.z; wA[c*4+3]=va.w;
            wB[c*4+0]=vb.x; wB[c*4+1]=vb.y; wB[c*4+2]=vb.z; wB[c*4+3]=vb.w;
        }
        const float4* c4 = (const float4*)&dWhh[gp * HID];
        const float4* d4 = (const float4*)&dWhh[(64 + gp) * HID];
        #pragma unroll
        for (int c = 0; c < 8; ++c) {
            float4 va = c4[c], vb = d4[c];
            wA[32+c*4+0]=va.x; wA[32+c*4+1]=va.y; wA[32+c*4+2]=va.z; wA[32+c*4+3]=va.w;
            wB[32+c*4+0]=vb.x; wB[32+c*4+1]=vb.y; wB[32+c*4+2]=vb.z; wB[32+c*4+3]=vb.w;
        }
    }
    const float bsA = dbih[gp]      + dbhh[gp];
    const float bsB = dbih[64 + gp] + dbhh[64 + gp];

    // ---- encoder (owner blocks 0..63, batch = blk), weights in padded LDS ----
    if (blk < NB) {
        for (int idx = tid; idx < G4 * 96; idx += NTHR) {
            int row = idx / 96, k = idx - row * 96;
            s_ew[row * EROW + k] = (k < EMB_E) ? eWih[row * EMB_E + k]
                                               : eWhh[row * HID + (k - EMB_E)];
        }
        const float ebsum = (tid < G4) ? (ebih[tid] + ebhh[tid]) : 0.0f;
        if (tid < HID) { s_ex[EMB_E + tid] = 0.0f; s_ecell[tid] = 0.0f; }
        __syncthreads();
        const int len = en_lens[blk];   // monotone mask -> stop at len
        for (int t = 0; t < len; ++t) {
            const int etok = en_batch[blk * S_EN + t];
            if (tid < EMB_E) s_ex[tid] = en_emb[(size_t)etok * EMB_E + tid];
            __syncthreads();
            if (tid < G4) {
                float g = ebsum;
                const float* wrow = &s_ew[tid * EROW];
                #pragma unroll
                for (int k = 0; k < 96; ++k) g = fmaf(s_ex[k], wrow[k], g);
                s_eg[tid] = g;
            }
            __syncthreads();
            if (tid < HID) {
                const float i  = sigmoidf_(s_eg[tid]);
                const float f  = sigmoidf_(s_eg[HID + tid]);
                const float gg = tanhf(s_eg[2*HID + tid]);
                const float o  = sigmoidf_(s_eg[3*HID + tid]);
                const float c  = f * s_ecell[tid] + i * gg;
                s_ecell[tid]   = c;
                s_ex[EMB_E + tid] = o * tanhf(c);
            }
            __syncthreads();
        }
        if (tid < HID) {
            hc_out[blk * 64 + tid]       = s_ex[EMB_E + tid];
            hc_out[blk * 64 + HID + tid] = s_ecell[tid];
        }
        __syncthreads();
        if (tid == 0) {
            __threadfence();
            __hip_atomic_store(&eflag[blk], 1, __ATOMIC_RELEASE, __HIP_MEMORY_SCOPE_AGENT);
        }
    }

    // ---- wait for all 64 encoder flags (no RMW: flag stores + load polls) ----
    for (;;) {
        if (wv == 0) {
            int f = __hip_atomic_load(&eflag[lane], __ATOMIC_ACQUIRE, __HIP_MEMORY_SCOPE_AGENT);
            ull bad = __ballot(f < 1);
            if (lane == 0) s_done = (bad == 0ull);
        }
        __syncthreads();
        if (s_done) break;
        __builtin_amdgcn_s_sleep(16);
        __syncthreads();
    }
    __threadfence();

    // ---- load h,c for my 32 batches; seed tokens ----
    {
        const int jb = tid >> 3, qd = tid & 7;
        const int gj = q * NJB + jb;
        float4 hq = *(const float4*)&hc_out[gj * 64 + qd * 4];
        float4 cq = *(const float4*)&hc_out[gj * 64 + 32 + qd * 4];
        *(float4*)&s_xh[jb * XROW + 32 + qd * 4] = hq;
        *(float4*)&s_c [jb * HID + qd * 4]       = cq;
        if (qd == 0) s_tok[jb] = de_batch[gj * S_DE + 0];
    }
    __syncthreads();

    // ---- decoder: 49 steps, ONE sync hop each ----
    for (int s = 1; s < S_DE; ++s) {
        // (a) gather x = de_emb[tok]
        {
            const int jb = tid >> 3, qd = tid & 7;
            const int tk = s_tok[jb];
            float4 xv = *(const float4*)&de_emb[(size_t)tk * EMB_D + qd * 4];
            *(float4*)&s_xh[jb * XROW + qd * 4] = xv;
        }
        __syncthreads();

        // (b) gates: 2 gates x 8 batches per thread, weights in VGPRs
        for (int j = 0; j < 8; ++j) {
            const int jloc = jh * 8 + j;
            const float4* x4 = (const float4*)&s_xh[jloc * XROW];
            float a = bsA, b2 = bsB;
            #pragma unroll
            for (int c = 0; c < 16; ++c) {
                const float4 v = x4[c];
                a = fmaf(v.x, wA[c*4+0], a);  b2 = fmaf(v.x, wB[c*4+0], b2);
                a = fmaf(v.y, wA[c*4+1], a);  b2 = fmaf(v.y, wB[c*4+1], b2);
                a = fmaf(v.z, wA[c*4+2], a);  b2 = fmaf(v.z, wB[c*4+2], b2);
                a = fmaf(v.w, wA[c*4+3], a);  b2 = fmaf(v.w, wB[c*4+3], b2);
            }
            s_g[jloc * GROWS + gp]      = a;
            s_g[jloc * GROWS + 64 + gp] = b2;
        }
        __syncthreads();

        // (c) activations + state update (4 units/thread)
        {
            const int jA = tid >> 3;
            const int u0 = (tid & 7) * 4;
            float4 iv = *(float4*)&s_g[jA * GROWS + u0];
            float4 fv = *(float4*)&s_g[jA * GROWS + 32 + u0];
            float4 gv = *(float4*)&s_g[jA * GROWS + 64 + u0];
            float4 ov = *(float4*)&s_g[jA * GROWS + 96 + u0];
            float4 cv = *(float4*)&s_c[jA * HID + u0];
            float4 hv;
            cv.x = sigmoidf_(fv.x) * cv.x + sigmoidf_(iv.x) * tanhf(gv.x);
            hv.x = sigmoidf_(ov.x) * tanhf(cv.x);
            cv.y = sigmoidf_(fv.y) * cv.y + sigmoidf_(iv.y) * tanhf(gv.y);
            hv.y = sigmoidf_(ov.y) * tanhf(cv.y);
            cv.z = sigmoidf_(fv.z) * cv.z + sigmoidf_(iv.z) * tanhf(gv.z);
            hv.z = sigmoidf_(ov.z) * tanhf(cv.z);
            cv.w = sigmoidf_(fv.w) * cv.w + sigmoidf_(iv.w) * tanhf(gv.w);
            hv.w = sigmoidf_(ov.w) * tanhf(cv.w);
            *(float4*)&s_c [jA * HID + u0]        = cv;
            *(float4*)&s_xh[jA * XROW + 32 + u0]  = hv;
        }
        __syncthreads();

        // (d) logits slice + packed argmax key per (batch, slice)
        const int par = s & 1;
        for (int jj = 0; jj < 8; ++jj) {
            const int jloc = wv * 8 + jj;
            const int gj   = q * NJB + jloc;
            const float4* hj4 = (const float4*)&s_xh[jloc * XROW + 32];
            float a0 = br[0], a1 = br[1], a2 = br[2];
            #pragma unroll
            for (int kc = 0; kc < 8; ++kc) {
                const float4 h4 = hj4[kc];
                a0 = fmaf(wr[0][kc*4+0], h4.x, a0); a1 = fmaf(wr[1][kc*4+0], h4.x, a1); a2 = fmaf(wr[2][kc*4+0], h4.x, a2);
                a0 = fmaf(wr[0][kc*4+1], h4.y, a0); a1 = fmaf(wr[1][kc*4+1], h4.y, a1); a2 = fmaf(wr[2][kc*4+1], h4.y, a2);
                a0 = fmaf(wr[0][kc*4+2], h4.z, a0); a1 = fmaf(wr[1][kc*4+2], h4.z, a1); a2 = fmaf(wr[2][kc*4+2], h4.z, a2);
                a0 = fmaf(wr[0][kc*4+3], h4.w, a0); a1 = fmaf(wr[1][kc*4+3], h4.w, a1); a2 = fmaf(wr[2][kc*4+3], h4.w, a2);
            }
            float* od = out + (size_t)gj * OUT_B + (size_t)s * DE_VSZ;
            ull key = 0ull;
            if (rv[0]) { od[grow[0]] = a0;
                key = ((ull)ordf_(a0) << 32) | (unsigned)~grow[0]; }
            if (rv[1]) { od[grow[1]] = a1;
                ull k2 = ((ull)ordf_(a1) << 32) | (unsigned)~grow[1];
                if (k2 > key) key = k2; }
            if (rv[2]) { od[grow[2]] = a2;
                ull k2 = ((ull)ordf_(a2) << 32) | (unsigned)~grow[2];
                if (k2 > key) key = k2; }
            #pragma unroll
            for (int off = 1; off < 64; off <<= 1) {
                const ull ok = __shfl_xor(key, off);
                if (ok > key) key = ok;
            }
            if (lane == 0) gkeys[(size_t)par * NB * ISL + (size_t)gj * ISL + isl] = key;
        }
        __syncthreads();
        if (tid == 0) {
            __threadfence();
            __hip_atomic_store(&sflag[q * ISL + isl], s, __ATOMIC_RELEASE, __HIP_MEMORY_SCOPE_AGENT);
        }

        // (e) poll my half's 128 flags; read keys; reduce tokens locally
        for (;;) {
            if (wv == 0) {
                int f0 = __hip_atomic_load(&sflag[q * ISL + lane],      __ATOMIC_ACQUIRE, __HIP_MEMORY_SCOPE_AGENT);
                int f1 = __hip_atomic_load(&sflag[q * ISL + 64 + lane], __ATOMIC_ACQUIRE, __HIP_MEMORY_SCOPE_AGENT);
                ull bad = __ballot((f0 < s) || (f1 < s));
                if (lane == 0) s_done = (bad == 0ull);
            }
            __syncthreads();
            if (s_done) break;
            __builtin_amdgcn_s_sleep(4);
            __syncthreads();
        }
        __threadfence();
        {
            const int jb = tid >> 3, sub = tid & 7;
            const ull* kb = gkeys + (size_t)par * NB * ISL
                                  + (size_t)(q * NJB + jb) * ISL + sub * 16;
            ull m = 0ull;
            #pragma unroll
            for (int i = 0; i < 16; ++i) { const ull k = kb[i]; if (k > m) m = k; }
            #pragma unroll
            for (int off = 1; off < 8; off <<= 1) {
                const ull ok = __shfl_xor(m, off);
                if (ok > m) m = ok;
            }
            if (sub == 0) s_tok[jb] = (int)(~(unsigned)m);
        }
        __syncthreads();
    }
}

extern "C" void kernel_launch(void* const* d_in, const int* in_sizes, int n_in,
                              void* d_out, int out_size, void* d_ws, size_t ws_size,
                              hipStream_t stream) {
    (void)in_sizes; (void)n_in; (void)out_size; (void)ws_size;
    const int*   en_batch = (const int*)  d_in[0];
    const int*   en_lens  = (const int*)  d_in[1];
    const int*   de_batch = (const int*)  d_in[2];
    const float* en_emb   = (const float*)d_in[3];
    const float* eWih     = (const float*)d_in[4];
    const float* eWhh     = (const float*)d_in[5];
    const float* ebih     = (const float*)d_in[6];
    const float* ebhh     = (const float*)d_in[7];
    const float* de_emb   = (const float*)d_in[8];
    const float* dWih     = (const float*)d_in[9];
    const float* dWhh     = (const float*)d_in[10];
    const float* dbih     = (const float*)d_in[11];
    const float* dbhh     = (const float*)d_in[12];
    const float* fcW      = (const float*)d_in[13];
    const float* fcb      = (const float*)d_in[14];
    float* out = (float*)d_out;

    char* ws = (char*)d_ws;
    int*   eflag  = (int*)(ws + 0);          // 256 B
    int*   sflag  = (int*)(ws + 256);        // 1 KB
    float* hc_out = (float*)(ws + 2048);     // 16 KB
    ull*   gkeys  = (ull*)(ws + 2048 + 16384); // 128 KB

    // zero flags only (d_ws is poisoned 0xAA before every launch)
    hipMemsetAsync(ws, 0, 2048, stream);

    seq2seq_onehop<<<NBLK, NTHR, 0, stream>>>(
        en_batch, en_lens, de_batch, en_emb, eWih, eWhh, ebih, ebhh,
        de_emb, dWih, dWhh, dbih, dbhh, fcW, fcb, out,
        eflag, sflag, hc_out, gkeys);
}